// Round 5
// baseline (515.022 us; speedup 1.0000x reference)
//
#include <hip/hip_runtime.h>
#include <hip/hip_bf16.h>

#define B_ 4
#define S_ 4096
#define E_ 1024
#define D_ 128

typedef unsigned short u16;
typedef __bf16 bf16x8 __attribute__((ext_vector_type(8)));
typedef unsigned short u16x8 __attribute__((ext_vector_type(8)));
typedef float f32x4 __attribute__((ext_vector_type(4)));

__device__ inline u16 f2bf(float f) {
    __bf16 h = (__bf16)f;
    return __builtin_bit_cast(u16, h);
}

// ---------------------------------------------------------------------------
// Kernel 0: W [E,D] f32 -> Wt [3][D][E] bf16 (proj 0 pre-scaled by 1/sqrt(D))
// ---------------------------------------------------------------------------
__global__ __launch_bounds__(256) void wt_kernel(const float* __restrict__ Wq,
                                                 const float* __restrict__ Wk,
                                                 const float* __restrict__ Wv,
                                                 u16* __restrict__ Wt) {
    int tid = blockIdx.x * 256 + threadIdx.x;       // 0 .. 3*131072-1
    int w = tid >> 17;                               // 131072 = 2^17
    int rem = tid & 131071;
    int d = rem >> 10;
    int e = rem & 1023;
    const float* W = (w == 0) ? Wq : ((w == 1) ? Wk : Wv);
    float v = W[e * D_ + d];
    if (w == 0) v *= 0.08838834764831845f;           // 1/sqrt(128)
    Wt[tid] = f2bf(v);
}

// ---------------------------------------------------------------------------
// Kernel 1: FUSED QKV projection with x staged ONCE per block in LDS (bf16,
// XOR-swizzled so A-frag ds_read_b128 is conflict-free). Block: 16 rows x
// 384 cols; wave wv covers cols [wv*96, wv*96+96) = 6 MFMA col-tiles.
// x traffic: 64 MB total (was 256 MB with per-wave redundant global reads).
// ---------------------------------------------------------------------------
__global__ __launch_bounds__(256) void qkv_fused(const float* __restrict__ x,
                                                 const u16* __restrict__ Wt,
                                                 u16* __restrict__ q,
                                                 u16* __restrict__ k,
                                                 u16* __restrict__ vT) {
    const int mtile = blockIdx.x * 16;
    const int wv = threadIdx.x >> 6;
    const int l = threadIdx.x & 63;
    const int g = l >> 4;
    const int c = l & 15;

    __shared__ __align__(16) u16 xl[16 * 1024];   // 32 KB, XOR-swizzled rows

    // ---- cooperative stage: 16 iterations, one row per iteration ----
    // thread t loads x[mtile+i][t*4 .. t*4+4) (coalesced 4KB/row), converts
    // to bf16, writes 8B at byte = row*2048 + ((col*2) ^ ((row&7)<<4)).
#pragma unroll 4
    for (int i = 0; i < 16; i++) {
        int col = threadIdx.x * 4;
        float4 xv = *(const float4*)(x + (size_t)(mtile + i) * E_ + col);
        ushort4 pk;
        pk.x = f2bf(xv.x); pk.y = f2bf(xv.y);
        pk.z = f2bf(xv.z); pk.w = f2bf(xv.w);
        int byte = i * 2048 + ((col * 2) ^ ((i & 7) << 4));
        *(ushort4*)((char*)xl + byte) = pk;
    }
    __syncthreads();

    // B pointers per col-tile
    const u16* wp[6];
#pragma unroll
    for (int ct = 0; ct < 6; ct++) {
        int gc = wv * 96 + ct * 16;          // global output col (tile base)
        int proj = gc >> 7;
        int dcol = gc & 127;
        wp[ct] = Wt + (size_t)proj * (D_ * E_) + (size_t)(dcol + c) * E_ + g * 8;
    }

    f32x4 acc[6] = {};

    for (int ks = 0; ks < E_ / 32; ks++) {
        // A-frag: row c, k = ks*32 + g*8 .. +8, from swizzled LDS
        int abyte = c * 2048 + (((ks * 32 + g * 8) * 2) ^ ((c & 7) << 4));
        u16x8 araw = *(const u16x8*)((char*)xl + abyte);
        bf16x8 av = __builtin_bit_cast(bf16x8, araw);
#pragma unroll
        for (int ct = 0; ct < 6; ct++) {
            bf16x8 bw = *(const bf16x8*)(wp[ct] + ks * 32);
            acc[ct] = __builtin_amdgcn_mfma_f32_16x16x32_bf16(av, bw, acc[ct], 0, 0, 0);
        }
    }

#pragma unroll
    for (int ct = 0; ct < 6; ct++) {
        int gc = wv * 96 + ct * 16;
        int proj = gc >> 7;
        int dcol = gc & 127;
        if (proj < 2) {
            u16* dst = proj ? k : q;
#pragma unroll
            for (int j = 0; j < 4; j++) {
                int row = mtile + g * 4 + j;
                dst[(size_t)row * D_ + dcol + c] = f2bf(acc[ct][j]);
            }
        } else {
            int srow = mtile + g * 4;
            int b = srow >> 12;
            int s = srow & 4095;
            ushort4 pk;
            pk.x = f2bf(acc[ct][0]);
            pk.y = f2bf(acc[ct][1]);
            pk.z = f2bf(acc[ct][2]);
            pk.w = f2bf(acc[ct][3]);
            *(ushort4*)(vT + ((size_t)(b * D_ + dcol + c)) * S_ + s) = pk;
        }
    }
}

// ---------------------------------------------------------------------------
// Kernel 2: flash attention, KV-split across the block's 4 waves.
// Grid 1024, XCD-chunk swizzled (each XCD serves exactly 1 batch: 2MB KV
// fits 4MB L2). Block: 16 q-rows; wave wv does KV tiles [wv*16, wv*16+16).
// LDS kept to ~17KB (combine in TWO 64-col passes through a 16KB buffer,
// plds unioned inside) -> 8 blocks/CU = 8 waves/SIMD (~92% occupancy).
// ---------------------------------------------------------------------------
__global__ __launch_bounds__(256, 8) void attn_kernel(const u16* __restrict__ q,
                                                      const u16* __restrict__ k,
                                                      const u16* __restrict__ vT,
                                                      float* __restrict__ out) {
    // bijective XCD-chunk swizzle (nwg=1024, 8 XCDs, chunk=128)
    int bid = blockIdx.x;
    int sw = (bid & 7) * 128 + (bid >> 3);
    const int b = sw >> 8;          // batch 0..3 (2 XCDs per batch)
    const int qt = sw & 255;        // q-tile 0..255 (16 rows)
    const int wv = threadIdx.x >> 6;
    const int l = threadIdx.x & 63;
    const int g = l >> 4;
    const int c = l & 15;
    const int qrow0 = qt * 16;

    __shared__ __align__(16) char smem[16384];    // union: plds (8KB) / co (16KB)
    __shared__ float cm[4][16], cl[4][16];
    u16* pw = (u16*)(smem + wv * 2048);           // per-wave 2KB P buffer
    float* co = (float*)smem;                      // combine half-buffer

    // Q fragments, hoisted (scaled already, via Wq)
    bf16x8 aq[4];
    const u16* qp = q + ((size_t)(b * S_ + qrow0 + c)) * D_ + g * 8;
#pragma unroll
    for (int ks = 0; ks < 4; ks++) aq[ks] = *(const bf16x8*)(qp + ks * 32);

    f32x4 o[8] = {};
    float m[4], ll[4];
#pragma unroll
    for (int j = 0; j < 4; j++) { m[j] = -1e30f; ll[j] = 0.0f; }

    const u16* kb = k + (size_t)b * S_ * D_;
    const u16* vb = vT + (size_t)b * D_ * S_;

    for (int kt = wv * 16; kt < wv * 16 + 16; kt++) {
        const int kvbase = kt * 64;

        // ---- S = Q K^T : 4 tiles of 16 kv-cols, K-dim 128 (4 MFMA steps) ----
        f32x4 s[4] = {};
#pragma unroll
        for (int t = 0; t < 4; t++) {
            const u16* kp = kb + ((size_t)(kvbase + t * 16 + c)) * D_ + g * 8;
#pragma unroll
            for (int ks = 0; ks < 4; ks++) {
                bf16x8 bk = *(const bf16x8*)(kp + ks * 32);
                s[t] = __builtin_amdgcn_mfma_f32_16x16x32_bf16(aq[ks], bk, s[t], 0, 0, 0);
            }
        }

        // ---- online softmax (rows live in 16-lane groups) ----
        float pv[4][4];
#pragma unroll
        for (int j = 0; j < 4; j++) {
            float tm = fmaxf(fmaxf(s[0][j], s[1][j]), fmaxf(s[2][j], s[3][j]));
            tm = fmaxf(tm, __shfl_xor(tm, 1));
            tm = fmaxf(tm, __shfl_xor(tm, 2));
            tm = fmaxf(tm, __shfl_xor(tm, 4));
            tm = fmaxf(tm, __shfl_xor(tm, 8));
            float mn = fmaxf(m[j], tm);
            float alpha = exp2f((m[j] - mn) * 1.44269504f);
            float rs = 0.f;
#pragma unroll
            for (int t = 0; t < 4; t++) {
                float p = exp2f((s[t][j] - mn) * 1.44269504f);
                pv[t][j] = p;
                rs += p;
            }
            rs += __shfl_xor(rs, 1);
            rs += __shfl_xor(rs, 2);
            rs += __shfl_xor(rs, 4);
            rs += __shfl_xor(rs, 8);
            ll[j] = ll[j] * alpha + rs;
            m[j] = mn;
#pragma unroll
            for (int ct = 0; ct < 8; ct++) o[ct][j] *= alpha;
        }

        // ---- P -> LDS (wave-private), XOR-swizzled ----
#pragma unroll
        for (int t = 0; t < 4; t++) {
#pragma unroll
            for (int j = 0; j < 4; j++) {
                int r = g * 4 + j;
                int cf = t * 16 + c;
                int slot = (cf >> 3) ^ ((r & 7) ^ ((r & 8) >> 2));
                pw[r * 64 + slot * 8 + (cf & 7)] = f2bf(pv[t][j]);
            }
        }

        // ---- PV: O += P[16,64] * V[64,128] ----
#pragma unroll
        for (int st = 0; st < 2; st++) {
            int rho = c;
            int sigma = g + st * 4;
            int slot = sigma ^ ((rho & 7) ^ ((rho & 8) >> 2));
            u16x8 praw = *(const u16x8*)(pw + rho * 64 + slot * 8);
            bf16x8 pa = __builtin_bit_cast(bf16x8, praw);
#pragma unroll
            for (int ct = 0; ct < 8; ct++) {
                const u16* vp = vb + ((size_t)(ct * 16 + c)) * S_ + kvbase + st * 32 + g * 8;
                bf16x8 bv = *(const bf16x8*)vp;
                o[ct] = __builtin_amdgcn_mfma_f32_16x16x32_bf16(pa, bv, o[ct], 0, 0, 0);
            }
        }
    }

    // ---- combine partials across the 4 waves, two 64-col passes ----
    __syncthreads();   // all waves done with pw before co overwrites it
#pragma unroll
    for (int ct = 0; ct < 4; ct++) {
#pragma unroll
        for (int j = 0; j < 4; j++)
            co[(wv * 16 + g * 4 + j) * 64 + ct * 16 + c] = o[ct][j];
    }
    if (c == 0) {
#pragma unroll
        for (int j = 0; j < 4; j++) {
            cm[wv][g * 4 + j] = m[j];
            cl[wv][g * 4 + j] = ll[j];
        }
    }
    __syncthreads();

    // per-thread output slice: row r, 4 cols at cb
    const int r = threadIdx.x >> 4;
    const int cb = (threadIdx.x & 15) * 4;
    float M = fmaxf(fmaxf(cm[0][r], cm[1][r]), fmaxf(cm[2][r], cm[3][r]));
    float ew[4];
    float Lsum = 0.f;
#pragma unroll
    for (int w = 0; w < 4; w++) {
        ew[w] = exp2f((cm[w][r] - M) * 1.44269504f);
        Lsum += cl[w][r] * ew[w];
    }
    const float rL = 1.0f / Lsum;
    float* op = out + ((size_t)(b * S_ + qrow0 + r)) * D_;

    {   // cols 0..63
        float4 res;
        float* rp = &res.x;
#pragma unroll
        for (int i = 0; i < 4; i++) {
            float a = 0.f;
#pragma unroll
            for (int w = 0; w < 4; w++) a += co[(w * 16 + r) * 64 + cb + i] * ew[w];
            rp[i] = a * rL;
        }
        *(float4*)(op + cb) = res;
    }
    __syncthreads();
#pragma unroll
    for (int ct = 4; ct < 8; ct++) {
#pragma unroll
        for (int j = 0; j < 4; j++)
            co[(wv * 16 + g * 4 + j) * 64 + (ct - 4) * 16 + c] = o[ct][j];
    }
    __syncthreads();
    {   // cols 64..127
        float4 res;
        float* rp = &res.x;
#pragma unroll
        for (int i = 0; i < 4; i++) {
            float a = 0.f;
#pragma unroll
            for (int w = 0; w < 4; w++) a += co[(w * 16 + r) * 64 + cb + i] * ew[w];
            rp[i] = a * rL;
        }
        *(float4*)(op + 64 + cb) = res;
    }
}

extern "C" void kernel_launch(void* const* d_in, const int* in_sizes, int n_in,
                              void* d_out, int out_size, void* d_ws, size_t ws_size,
                              hipStream_t stream) {
    const float* x  = (const float*)d_in[0];
    const float* Wq = (const float*)d_in[1];
    const float* Wk = (const float*)d_in[2];
    const float* Wv = (const float*)d_in[3];
    float* out = (float*)d_out;   // reference output dtype is float32

    // workspace layout (bytes): q 4MB | k 4MB | vT 4MB | Wt 768KB
    u16* q  = (u16*)d_ws;
    u16* k  = q  + (size_t)B_ * S_ * D_;
    u16* vT = k  + (size_t)B_ * S_ * D_;
    u16* Wt = vT + (size_t)B_ * S_ * D_;

    wt_kernel<<<(3 * D_ * E_) / 256, 256, 0, stream>>>(Wq, Wk, Wv, Wt);
    qkv_fused<<<(B_ * S_) / 16, 256, 0, stream>>>(x, Wt, q, k, vT);
    attn_kernel<<<(B_ * S_) / 16, 256, 0, stream>>>(q, k, vT, out);
}

// Round 6
// 339.752 us; speedup vs baseline: 1.5159x; 1.5159x over previous
//
#include <hip/hip_runtime.h>
#include <hip/hip_bf16.h>

#define B_ 4
#define S_ 4096
#define E_ 1024
#define D_ 128

typedef unsigned short u16;
typedef __bf16 bf16x8 __attribute__((ext_vector_type(8)));
typedef unsigned short u16x8 __attribute__((ext_vector_type(8)));
typedef float f32x4 __attribute__((ext_vector_type(4)));

__device__ inline u16 f2bf(float f) {
    __bf16 h = (__bf16)f;
    return __builtin_bit_cast(u16, h);
}

// ---------------------------------------------------------------------------
// Kernel 0: W [E,D] f32 -> Wt [3][D][E] bf16 (proj 0 pre-scaled by 1/sqrt(D))
// ---------------------------------------------------------------------------
__global__ __launch_bounds__(256) void wt_kernel(const float* __restrict__ Wq,
                                                 const float* __restrict__ Wk,
                                                 const float* __restrict__ Wv,
                                                 u16* __restrict__ Wt) {
    int tid = blockIdx.x * 256 + threadIdx.x;       // 0 .. 3*131072-1
    int w = tid >> 17;                               // 131072 = 2^17
    int rem = tid & 131071;
    int d = rem >> 10;
    int e = rem & 1023;
    const float* W = (w == 0) ? Wq : ((w == 1) ? Wk : Wv);
    float v = W[e * D_ + d];
    if (w == 0) v *= 0.08838834764831845f;           // 1/sqrt(128)
    Wt[tid] = f2bf(v);
}

// ---------------------------------------------------------------------------
// Kernel 1: FUSED QKV projection with x staged ONCE per block in LDS (bf16,
// XOR-swizzled so A-frag ds_read_b128 is conflict-free). Block: 16 rows x
// 384 cols; wave wv covers cols [wv*96, wv*96+96) = 6 MFMA col-tiles.
// ---------------------------------------------------------------------------
__global__ __launch_bounds__(256) void qkv_fused(const float* __restrict__ x,
                                                 const u16* __restrict__ Wt,
                                                 u16* __restrict__ q,
                                                 u16* __restrict__ k,
                                                 u16* __restrict__ vT) {
    const int mtile = blockIdx.x * 16;
    const int wv = threadIdx.x >> 6;
    const int l = threadIdx.x & 63;
    const int g = l >> 4;
    const int c = l & 15;

    __shared__ __align__(16) u16 xl[16 * 1024];   // 32 KB, XOR-swizzled rows

#pragma unroll 4
    for (int i = 0; i < 16; i++) {
        int col = threadIdx.x * 4;
        float4 xv = *(const float4*)(x + (size_t)(mtile + i) * E_ + col);
        ushort4 pk;
        pk.x = f2bf(xv.x); pk.y = f2bf(xv.y);
        pk.z = f2bf(xv.z); pk.w = f2bf(xv.w);
        int byte = i * 2048 + ((col * 2) ^ ((i & 7) << 4));
        *(ushort4*)((char*)xl + byte) = pk;
    }
    __syncthreads();

    const u16* wp[6];
#pragma unroll
    for (int ct = 0; ct < 6; ct++) {
        int gc = wv * 96 + ct * 16;          // global output col (tile base)
        int proj = gc >> 7;
        int dcol = gc & 127;
        wp[ct] = Wt + (size_t)proj * (D_ * E_) + (size_t)(dcol + c) * E_ + g * 8;
    }

    f32x4 acc[6] = {};

    for (int ks = 0; ks < E_ / 32; ks++) {
        int abyte = c * 2048 + (((ks * 32 + g * 8) * 2) ^ ((c & 7) << 4));
        u16x8 araw = *(const u16x8*)((char*)xl + abyte);
        bf16x8 av = __builtin_bit_cast(bf16x8, araw);
#pragma unroll
        for (int ct = 0; ct < 6; ct++) {
            bf16x8 bw = *(const bf16x8*)(wp[ct] + ks * 32);
            acc[ct] = __builtin_amdgcn_mfma_f32_16x16x32_bf16(av, bw, acc[ct], 0, 0, 0);
        }
    }

#pragma unroll
    for (int ct = 0; ct < 6; ct++) {
        int gc = wv * 96 + ct * 16;
        int proj = gc >> 7;
        int dcol = gc & 127;
        if (proj < 2) {
            u16* dst = proj ? k : q;
#pragma unroll
            for (int j = 0; j < 4; j++) {
                int row = mtile + g * 4 + j;
                dst[(size_t)row * D_ + dcol + c] = f2bf(acc[ct][j]);
            }
        } else {
            int srow = mtile + g * 4;
            int b = srow >> 12;
            int s = srow & 4095;
            ushort4 pk;
            pk.x = f2bf(acc[ct][0]);
            pk.y = f2bf(acc[ct][1]);
            pk.z = f2bf(acc[ct][2]);
            pk.w = f2bf(acc[ct][3]);
            *(ushort4*)(vT + ((size_t)(b * D_ + dcol + c)) * S_ + s) = pk;
        }
    }
}

// ---------------------------------------------------------------------------
// Kernel 2: flash attention, KV-split across the block's 4 waves.
// Grid 1024, XCD-chunk swizzled. Block: 16 q-rows; wave wv does KV tiles
// [wv*16, wv*16+16). LDS ~17KB (combine in two 64-col passes).
// __launch_bounds__(256, 4): r5's (256,8) squeezed VGPR 64->32 and spilled
// the o[] accumulators to scratch (FETCH 15MB->637MB, dur 254->428us).
// With VGPR=64 and 17KB LDS, runtime occupancy reaches 8 blocks/CU anyway.
// ---------------------------------------------------------------------------
__global__ __launch_bounds__(256, 4) void attn_kernel(const u16* __restrict__ q,
                                                      const u16* __restrict__ k,
                                                      const u16* __restrict__ vT,
                                                      float* __restrict__ out) {
    // bijective XCD-chunk swizzle (nwg=1024, 8 XCDs, chunk=128)
    int bid = blockIdx.x;
    int sw = (bid & 7) * 128 + (bid >> 3);
    const int b = sw >> 8;          // batch 0..3 (2 XCDs per batch)
    const int qt = sw & 255;        // q-tile 0..255 (16 rows)
    const int wv = threadIdx.x >> 6;
    const int l = threadIdx.x & 63;
    const int g = l >> 4;
    const int c = l & 15;
    const int qrow0 = qt * 16;

    __shared__ __align__(16) char smem[16384];    // union: plds (8KB) / co (16KB)
    __shared__ float cm[4][16], cl[4][16];
    u16* pw = (u16*)(smem + wv * 2048);           // per-wave 2KB P buffer
    float* co = (float*)smem;                      // combine half-buffer

    // Q fragments, hoisted (scaled already, via Wq)
    bf16x8 aq[4];
    const u16* qp = q + ((size_t)(b * S_ + qrow0 + c)) * D_ + g * 8;
#pragma unroll
    for (int ks = 0; ks < 4; ks++) aq[ks] = *(const bf16x8*)(qp + ks * 32);

    f32x4 o[8] = {};
    float m[4], ll[4];
#pragma unroll
    for (int j = 0; j < 4; j++) { m[j] = -1e30f; ll[j] = 0.0f; }

    const u16* kb = k + (size_t)b * S_ * D_;
    const u16* vb = vT + (size_t)b * D_ * S_;

    for (int kt = wv * 16; kt < wv * 16 + 16; kt++) {
        const int kvbase = kt * 64;

        // ---- S = Q K^T : 4 tiles of 16 kv-cols, K-dim 128 (4 MFMA steps) ----
        f32x4 s[4] = {};
#pragma unroll
        for (int t = 0; t < 4; t++) {
            const u16* kp = kb + ((size_t)(kvbase + t * 16 + c)) * D_ + g * 8;
#pragma unroll
            for (int ks = 0; ks < 4; ks++) {
                bf16x8 bk = *(const bf16x8*)(kp + ks * 32);
                s[t] = __builtin_amdgcn_mfma_f32_16x16x32_bf16(aq[ks], bk, s[t], 0, 0, 0);
            }
        }

        // ---- online softmax (rows live in 16-lane groups) ----
        float pv[4][4];
#pragma unroll
        for (int j = 0; j < 4; j++) {
            float tm = fmaxf(fmaxf(s[0][j], s[1][j]), fmaxf(s[2][j], s[3][j]));
            tm = fmaxf(tm, __shfl_xor(tm, 1));
            tm = fmaxf(tm, __shfl_xor(tm, 2));
            tm = fmaxf(tm, __shfl_xor(tm, 4));
            tm = fmaxf(tm, __shfl_xor(tm, 8));
            float mn = fmaxf(m[j], tm);
            float alpha = exp2f((m[j] - mn) * 1.44269504f);
            float rs = 0.f;
#pragma unroll
            for (int t = 0; t < 4; t++) {
                float p = exp2f((s[t][j] - mn) * 1.44269504f);
                pv[t][j] = p;
                rs += p;
            }
            rs += __shfl_xor(rs, 1);
            rs += __shfl_xor(rs, 2);
            rs += __shfl_xor(rs, 4);
            rs += __shfl_xor(rs, 8);
            ll[j] = ll[j] * alpha + rs;
            m[j] = mn;
#pragma unroll
            for (int ct = 0; ct < 8; ct++) o[ct][j] *= alpha;
        }

        // ---- P -> LDS (wave-private), XOR-swizzled ----
#pragma unroll
        for (int t = 0; t < 4; t++) {
#pragma unroll
            for (int j = 0; j < 4; j++) {
                int r = g * 4 + j;
                int cf = t * 16 + c;
                int slot = (cf >> 3) ^ ((r & 7) ^ ((r & 8) >> 2));
                pw[r * 64 + slot * 8 + (cf & 7)] = f2bf(pv[t][j]);
            }
        }

        // ---- PV: O += P[16,64] * V[64,128] ----
#pragma unroll
        for (int st = 0; st < 2; st++) {
            int rho = c;
            int sigma = g + st * 4;
            int slot = sigma ^ ((rho & 7) ^ ((rho & 8) >> 2));
            u16x8 praw = *(const u16x8*)(pw + rho * 64 + slot * 8);
            bf16x8 pa = __builtin_bit_cast(bf16x8, praw);
#pragma unroll
            for (int ct = 0; ct < 8; ct++) {
                const u16* vp = vb + ((size_t)(ct * 16 + c)) * S_ + kvbase + st * 32 + g * 8;
                bf16x8 bv = *(const bf16x8*)vp;
                o[ct] = __builtin_amdgcn_mfma_f32_16x16x32_bf16(pa, bv, o[ct], 0, 0, 0);
            }
        }
    }

    // ---- combine partials across the 4 waves, two 64-col passes ----
    __syncthreads();   // all waves done with pw before co overwrites it
#pragma unroll
    for (int ct = 0; ct < 4; ct++) {
#pragma unroll
        for (int j = 0; j < 4; j++)
            co[(wv * 16 + g * 4 + j) * 64 + ct * 16 + c] = o[ct][j];
    }
    if (c == 0) {
#pragma unroll
        for (int j = 0; j < 4; j++) {
            cm[wv][g * 4 + j] = m[j];
            cl[wv][g * 4 + j] = ll[j];
        }
    }
    __syncthreads();

    // per-thread output slice: row r, 4 cols at cb
    const int r = threadIdx.x >> 4;
    const int cb = (threadIdx.x & 15) * 4;
    float M = fmaxf(fmaxf(cm[0][r], cm[1][r]), fmaxf(cm[2][r], cm[3][r]));
    float ew[4];
    float Lsum = 0.f;
#pragma unroll
    for (int w = 0; w < 4; w++) {
        ew[w] = exp2f((cm[w][r] - M) * 1.44269504f);
        Lsum += cl[w][r] * ew[w];
    }
    const float rL = 1.0f / Lsum;
    float* op = out + ((size_t)(b * S_ + qrow0 + r)) * D_;

    {   // cols 0..63
        float4 res;
        float* rp = &res.x;
#pragma unroll
        for (int i = 0; i < 4; i++) {
            float a = 0.f;
#pragma unroll
            for (int w = 0; w < 4; w++) a += co[(w * 16 + r) * 64 + cb + i] * ew[w];
            rp[i] = a * rL;
        }
        *(float4*)(op + cb) = res;
    }
    __syncthreads();
#pragma unroll
    for (int ct = 4; ct < 8; ct++) {
#pragma unroll
        for (int j = 0; j < 4; j++)
            co[(wv * 16 + g * 4 + j) * 64 + (ct - 4) * 16 + c] = o[ct][j];
    }
    __syncthreads();
    {   // cols 64..127
        float4 res;
        float* rp = &res.x;
#pragma unroll
        for (int i = 0; i < 4; i++) {
            float a = 0.f;
#pragma unroll
            for (int w = 0; w < 4; w++) a += co[(w * 16 + r) * 64 + cb + i] * ew[w];
            rp[i] = a * rL;
        }
        *(float4*)(op + 64 + cb) = res;
    }
}

extern "C" void kernel_launch(void* const* d_in, const int* in_sizes, int n_in,
                              void* d_out, int out_size, void* d_ws, size_t ws_size,
                              hipStream_t stream) {
    const float* x  = (const float*)d_in[0];
    const float* Wq = (const float*)d_in[1];
    const float* Wk = (const float*)d_in[2];
    const float* Wv = (const float*)d_in[3];
    float* out = (float*)d_out;   // reference output dtype is float32

    // workspace layout (bytes): q 4MB | k 4MB | vT 4MB | Wt 768KB
    u16* q  = (u16*)d_ws;
    u16* k  = q  + (size_t)B_ * S_ * D_;
    u16* vT = k  + (size_t)B_ * S_ * D_;
    u16* Wt = vT + (size_t)B_ * S_ * D_;

    wt_kernel<<<(3 * D_ * E_) / 256, 256, 0, stream>>>(Wq, Wk, Wv, Wt);
    qkv_fused<<<(B_ * S_) / 16, 256, 0, stream>>>(x, Wt, q, k, vT);
    attn_kernel<<<(B_ * S_) / 16, 256, 0, stream>>>(q, k, vT, out);
}

// Round 7
// 338.355 us; speedup vs baseline: 1.5221x; 1.0041x over previous
//
#include <hip/hip_runtime.h>
#include <hip/hip_bf16.h>

#define B_ 4
#define S_ 4096
#define E_ 1024
#define D_ 128

typedef unsigned short u16;
typedef __bf16 bf16x8 __attribute__((ext_vector_type(8)));
typedef unsigned short u16x8 __attribute__((ext_vector_type(8)));
typedef float f32x4 __attribute__((ext_vector_type(4)));

__device__ inline u16 f2bf(float f) {
    __bf16 h = (__bf16)f;
    return __builtin_bit_cast(u16, h);
}

// ---------------------------------------------------------------------------
// Kernel 0: W [E,D] f32 -> Wt [3][D][E] bf16 (proj 0 pre-scaled by 1/sqrt(D))
// ---------------------------------------------------------------------------
__global__ __launch_bounds__(256) void wt_kernel(const float* __restrict__ Wq,
                                                 const float* __restrict__ Wk,
                                                 const float* __restrict__ Wv,
                                                 u16* __restrict__ Wt) {
    int tid = blockIdx.x * 256 + threadIdx.x;       // 0 .. 3*131072-1
    int w = tid >> 17;                               // 131072 = 2^17
    int rem = tid & 131071;
    int d = rem >> 10;
    int e = rem & 1023;
    const float* W = (w == 0) ? Wq : ((w == 1) ? Wk : Wv);
    float v = W[e * D_ + d];
    if (w == 0) v *= 0.08838834764831845f;           // 1/sqrt(128)
    Wt[tid] = f2bf(v);
}

// ---------------------------------------------------------------------------
// Kernel 1: FUSED QKV projection, 512 threads (8 waves) per block.
// Block: 16 rows x 384 cols; wave wv covers cols [wv*48, wv*48+48) = 3
// MFMA col-tiles. x staged ONCE per block in LDS (bf16, XOR-swizzled).
// Grid 1024 -> 8192 waves (was 4096: grid-capped occupancy at 50%).
// ---------------------------------------------------------------------------
__global__ __launch_bounds__(512) void qkv_fused(const float* __restrict__ x,
                                                 const u16* __restrict__ Wt,
                                                 u16* __restrict__ q,
                                                 u16* __restrict__ k,
                                                 u16* __restrict__ vT) {
    const int mtile = blockIdx.x * 16;
    const int wv = threadIdx.x >> 6;       // 0..7
    const int l = threadIdx.x & 63;
    const int g = l >> 4;
    const int c = l & 15;

    __shared__ __align__(16) u16 xl[16 * 1024];   // 32 KB, XOR-swizzled rows

    // cooperative stage: 512 threads, 8 iterations, 2 rows per iteration
#pragma unroll 4
    for (int i = 0; i < 8; i++) {
        int row = i * 2 + (threadIdx.x >> 8);
        int col = (threadIdx.x & 255) * 4;
        float4 xv = *(const float4*)(x + (size_t)(mtile + row) * E_ + col);
        ushort4 pk;
        pk.x = f2bf(xv.x); pk.y = f2bf(xv.y);
        pk.z = f2bf(xv.z); pk.w = f2bf(xv.w);
        int byte = row * 2048 + ((col * 2) ^ ((row & 7) << 4));
        *(ushort4*)((char*)xl + byte) = pk;
    }
    __syncthreads();

    const u16* wp[3];
#pragma unroll
    for (int ct = 0; ct < 3; ct++) {
        int gc = wv * 48 + ct * 16;          // global output col (tile base)
        int proj = gc >> 7;
        int dcol = gc & 127;
        wp[ct] = Wt + (size_t)proj * (D_ * E_) + (size_t)(dcol + c) * E_ + g * 8;
    }

    f32x4 acc[3] = {};

    for (int ks = 0; ks < E_ / 32; ks++) {
        int abyte = c * 2048 + (((ks * 32 + g * 8) * 2) ^ ((c & 7) << 4));
        u16x8 araw = *(const u16x8*)((char*)xl + abyte);
        bf16x8 av = __builtin_bit_cast(bf16x8, araw);
#pragma unroll
        for (int ct = 0; ct < 3; ct++) {
            bf16x8 bw = *(const bf16x8*)(wp[ct] + ks * 32);
            acc[ct] = __builtin_amdgcn_mfma_f32_16x16x32_bf16(av, bw, acc[ct], 0, 0, 0);
        }
    }

#pragma unroll
    for (int ct = 0; ct < 3; ct++) {
        int gc = wv * 48 + ct * 16;
        int proj = gc >> 7;
        int dcol = gc & 127;
        if (proj < 2) {
            u16* dst = proj ? k : q;
#pragma unroll
            for (int j = 0; j < 4; j++) {
                int row = mtile + g * 4 + j;
                dst[(size_t)row * D_ + dcol + c] = f2bf(acc[ct][j]);
            }
        } else {
            int srow = mtile + g * 4;
            int b = srow >> 12;
            int s = srow & 4095;
            ushort4 pk;
            pk.x = f2bf(acc[ct][0]);
            pk.y = f2bf(acc[ct][1]);
            pk.z = f2bf(acc[ct][2]);
            pk.w = f2bf(acc[ct][3]);
            *(ushort4*)(vT + ((size_t)(b * D_ + dcol + c)) * S_ + s) = pk;
        }
    }
}

// ---------------------------------------------------------------------------
// Kernel 2: flash attention, KV-split across 8 waves (512 threads).
// Grid 1024, XCD-chunk swizzled. Block: 16 q-rows; wave wv does KV tiles
// [wv*8, wv*8+8) of 64 rows. 8192 waves total -> 32 waves/CU possible
// (r6 was grid-capped at 16 waves/CU = 46% occupancy).
// LDS ~34KB: co combine (32KB, 8 waves x 16 rows x 64 cols f32, two
// column passes) unioned over the 8 x 2KB plds. 4 blocks/CU by LDS.
// ---------------------------------------------------------------------------
__global__ __launch_bounds__(512, 4) void attn_kernel(const u16* __restrict__ q,
                                                      const u16* __restrict__ k,
                                                      const u16* __restrict__ vT,
                                                      float* __restrict__ out) {
    // bijective XCD-chunk swizzle (nwg=1024, 8 XCDs, chunk=128)
    int bid = blockIdx.x;
    int sw = (bid & 7) * 128 + (bid >> 3);
    const int b = sw >> 8;          // batch 0..3 (2 XCDs per batch)
    const int qt = sw & 255;        // q-tile 0..255 (16 rows)
    const int wv = threadIdx.x >> 6;    // 0..7
    const int l = threadIdx.x & 63;
    const int g = l >> 4;
    const int c = l & 15;
    const int qrow0 = qt * 16;

    __shared__ __align__(16) char smem[32768];    // union: plds (16KB) / co (32KB)
    __shared__ float cm[8][16], cl[8][16];
    u16* pw = (u16*)(smem + wv * 2048);           // per-wave 2KB P buffer
    float* co = (float*)smem;                      // combine half-buffer

    // Q fragments, hoisted (scaled already, via Wq)
    bf16x8 aq[4];
    const u16* qp = q + ((size_t)(b * S_ + qrow0 + c)) * D_ + g * 8;
#pragma unroll
    for (int ks = 0; ks < 4; ks++) aq[ks] = *(const bf16x8*)(qp + ks * 32);

    f32x4 o[8] = {};
    float m[4], ll[4];
#pragma unroll
    for (int j = 0; j < 4; j++) { m[j] = -1e30f; ll[j] = 0.0f; }

    const u16* kb = k + (size_t)b * S_ * D_;
    const u16* vb = vT + (size_t)b * D_ * S_;

    for (int kt = wv * 8; kt < wv * 8 + 8; kt++) {
        const int kvbase = kt * 64;

        // ---- S = Q K^T : 4 tiles of 16 kv-cols, K-dim 128 (4 MFMA steps) ----
        f32x4 s[4] = {};
#pragma unroll
        for (int t = 0; t < 4; t++) {
            const u16* kp = kb + ((size_t)(kvbase + t * 16 + c)) * D_ + g * 8;
#pragma unroll
            for (int ks = 0; ks < 4; ks++) {
                bf16x8 bk = *(const bf16x8*)(kp + ks * 32);
                s[t] = __builtin_amdgcn_mfma_f32_16x16x32_bf16(aq[ks], bk, s[t], 0, 0, 0);
            }
        }

        // ---- online softmax (rows live in 16-lane groups) ----
        float pv[4][4];
#pragma unroll
        for (int j = 0; j < 4; j++) {
            float tm = fmaxf(fmaxf(s[0][j], s[1][j]), fmaxf(s[2][j], s[3][j]));
            tm = fmaxf(tm, __shfl_xor(tm, 1));
            tm = fmaxf(tm, __shfl_xor(tm, 2));
            tm = fmaxf(tm, __shfl_xor(tm, 4));
            tm = fmaxf(tm, __shfl_xor(tm, 8));
            float mn = fmaxf(m[j], tm);
            float alpha = exp2f((m[j] - mn) * 1.44269504f);
            float rs = 0.f;
#pragma unroll
            for (int t = 0; t < 4; t++) {
                float p = exp2f((s[t][j] - mn) * 1.44269504f);
                pv[t][j] = p;
                rs += p;
            }
            rs += __shfl_xor(rs, 1);
            rs += __shfl_xor(rs, 2);
            rs += __shfl_xor(rs, 4);
            rs += __shfl_xor(rs, 8);
            ll[j] = ll[j] * alpha + rs;
            m[j] = mn;
#pragma unroll
            for (int ct = 0; ct < 8; ct++) o[ct][j] *= alpha;
        }

        // ---- P -> LDS (wave-private), XOR-swizzled ----
#pragma unroll
        for (int t = 0; t < 4; t++) {
#pragma unroll
            for (int j = 0; j < 4; j++) {
                int r = g * 4 + j;
                int cf = t * 16 + c;
                int slot = (cf >> 3) ^ ((r & 7) ^ ((r & 8) >> 2));
                pw[r * 64 + slot * 8 + (cf & 7)] = f2bf(pv[t][j]);
            }
        }

        // ---- PV: O += P[16,64] * V[64,128] ----
#pragma unroll
        for (int st = 0; st < 2; st++) {
            int rho = c;
            int sigma = g + st * 4;
            int slot = sigma ^ ((rho & 7) ^ ((rho & 8) >> 2));
            u16x8 praw = *(const u16x8*)(pw + rho * 64 + slot * 8);
            bf16x8 pa = __builtin_bit_cast(bf16x8, praw);
#pragma unroll
            for (int ct = 0; ct < 8; ct++) {
                const u16* vp = vb + ((size_t)(ct * 16 + c)) * S_ + kvbase + st * 32 + g * 8;
                bf16x8 bv = *(const bf16x8*)vp;
                o[ct] = __builtin_amdgcn_mfma_f32_16x16x32_bf16(pa, bv, o[ct], 0, 0, 0);
            }
        }
    }

    // ---- combine partials across the 8 waves, two 64-col passes ----
    __syncthreads();   // all waves done with pw before co overwrites it
#pragma unroll
    for (int ct = 0; ct < 4; ct++) {
#pragma unroll
        for (int j = 0; j < 4; j++)
            co[(wv * 16 + g * 4 + j) * 64 + ct * 16 + c] = o[ct][j];
    }
    if (c == 0) {
#pragma unroll
        for (int j = 0; j < 4; j++) {
            cm[wv][g * 4 + j] = m[j];
            cl[wv][g * 4 + j] = ll[j];
        }
    }
    __syncthreads();

    // per-thread output slice: row r, 2 cols at cb (512 threads, 16x64 grid)
    const int r = threadIdx.x >> 5;
    const int cb = (threadIdx.x & 31) * 2;
    float M = cm[0][r];
#pragma unroll
    for (int w = 1; w < 8; w++) M = fmaxf(M, cm[w][r]);
    float ew[8];
    float Lsum = 0.f;
#pragma unroll
    for (int w = 0; w < 8; w++) {
        ew[w] = exp2f((cm[w][r] - M) * 1.44269504f);
        Lsum += cl[w][r] * ew[w];
    }
    const float rL = 1.0f / Lsum;
    float* op = out + ((size_t)(b * S_ + qrow0 + r)) * D_;

    {   // cols 0..63
        float2 res;
#pragma unroll
        for (int i = 0; i < 2; i++) {
            float a = 0.f;
#pragma unroll
            for (int w = 0; w < 8; w++) a += co[(w * 16 + r) * 64 + cb + i] * ew[w];
            (&res.x)[i] = a * rL;
        }
        *(float2*)(op + cb) = res;
    }
    __syncthreads();
#pragma unroll
    for (int ct = 4; ct < 8; ct++) {
#pragma unroll
        for (int j = 0; j < 4; j++)
            co[(wv * 16 + g * 4 + j) * 64 + (ct - 4) * 16 + c] = o[ct][j];
    }
    __syncthreads();
    {   // cols 64..127
        float2 res;
#pragma unroll
        for (int i = 0; i < 2; i++) {
            float a = 0.f;
#pragma unroll
            for (int w = 0; w < 8; w++) a += co[(w * 16 + r) * 64 + cb + i] * ew[w];
            (&res.x)[i] = a * rL;
        }
        *(float2*)(op + 64 + cb) = res;
    }
}

extern "C" void kernel_launch(void* const* d_in, const int* in_sizes, int n_in,
                              void* d_out, int out_size, void* d_ws, size_t ws_size,
                              hipStream_t stream) {
    const float* x  = (const float*)d_in[0];
    const float* Wq = (const float*)d_in[1];
    const float* Wk = (const float*)d_in[2];
    const float* Wv = (const float*)d_in[3];
    float* out = (float*)d_out;   // reference output dtype is float32

    // workspace layout (bytes): q 4MB | k 4MB | vT 4MB | Wt 768KB
    u16* q  = (u16*)d_ws;
    u16* k  = q  + (size_t)B_ * S_ * D_;
    u16* vT = k  + (size_t)B_ * S_ * D_;
    u16* Wt = vT + (size_t)B_ * S_ * D_;

    wt_kernel<<<(3 * D_ * E_) / 256, 256, 0, stream>>>(Wq, Wk, Wv, Wt);
    qkv_fused<<<(B_ * S_) / 16, 512, 0, stream>>>(x, Wt, q, k, vT);
    attn_kernel<<<(B_ * S_) / 16, 512, 0, stream>>>(q, k, vT, out);
}

// Round 8
// 238.064 us; speedup vs baseline: 2.1634x; 1.4213x over previous
//
#include <hip/hip_runtime.h>
#include <hip/hip_bf16.h>

#define B_ 4
#define S_ 4096
#define E_ 1024
#define D_ 128

typedef unsigned short u16;
typedef __bf16 bf16x8 __attribute__((ext_vector_type(8)));
typedef unsigned short u16x8 __attribute__((ext_vector_type(8)));
typedef float f32x4 __attribute__((ext_vector_type(4)));

__device__ inline u16 f2bf(float f) {
    __bf16 h = (__bf16)f;
    return __builtin_bit_cast(u16, h);
}

// direct global->LDS DMA, 16B per lane, no VGPR round-trip
__device__ inline void gload16(const void* g, void* l) {
    __builtin_amdgcn_global_load_lds(
        (const __attribute__((address_space(1))) void*)g,
        (__attribute__((address_space(3))) void*)l, 16, 0, 0);
}

// ---------------------------------------------------------------------------
// Kernel 0: W [E,D] f32 -> Wt [3][D][E] bf16 (proj 0 pre-scaled by 1/sqrt(D))
// ---------------------------------------------------------------------------
__global__ __launch_bounds__(256) void wt_kernel(const float* __restrict__ Wq,
                                                 const float* __restrict__ Wk,
                                                 const float* __restrict__ Wv,
                                                 u16* __restrict__ Wt) {
    int tid = blockIdx.x * 256 + threadIdx.x;       // 0 .. 3*131072-1
    int w = tid >> 17;                               // 131072 = 2^17
    int rem = tid & 131071;
    int d = rem >> 10;
    int e = rem & 1023;
    const float* W = (w == 0) ? Wq : ((w == 1) ? Wk : Wv);
    float v = W[e * D_ + d];
    if (w == 0) v *= 0.08838834764831845f;           // 1/sqrt(128)
    Wt[tid] = f2bf(v);
}

// ---------------------------------------------------------------------------
// Kernel 1: FUSED QKV projection, 512 threads (8 waves) per block.
// Block: 16 rows x 384 cols; wave wv covers cols [wv*48, wv*48+48) = 3
// MFMA col-tiles. x staged ONCE per block in LDS (bf16, XOR-swizzled).
// ---------------------------------------------------------------------------
__global__ __launch_bounds__(512) void qkv_fused(const float* __restrict__ x,
                                                 const u16* __restrict__ Wt,
                                                 u16* __restrict__ q,
                                                 u16* __restrict__ k,
                                                 u16* __restrict__ vT) {
    const int mtile = blockIdx.x * 16;
    const int wv = threadIdx.x >> 6;       // 0..7
    const int l = threadIdx.x & 63;
    const int g = l >> 4;
    const int c = l & 15;

    __shared__ __align__(16) u16 xl[16 * 1024];   // 32 KB, XOR-swizzled rows

    // cooperative stage: 512 threads, 8 iterations, 2 rows per iteration
#pragma unroll 4
    for (int i = 0; i < 8; i++) {
        int row = i * 2 + (threadIdx.x >> 8);
        int col = (threadIdx.x & 255) * 4;
        float4 xv = *(const float4*)(x + (size_t)(mtile + row) * E_ + col);
        ushort4 pk;
        pk.x = f2bf(xv.x); pk.y = f2bf(xv.y);
        pk.z = f2bf(xv.z); pk.w = f2bf(xv.w);
        int byte = row * 2048 + ((col * 2) ^ ((row & 7) << 4));
        *(ushort4*)((char*)xl + byte) = pk;
    }
    __syncthreads();

    const u16* wp[3];
#pragma unroll
    for (int ct = 0; ct < 3; ct++) {
        int gc = wv * 48 + ct * 16;          // global output col (tile base)
        int proj = gc >> 7;
        int dcol = gc & 127;
        wp[ct] = Wt + (size_t)proj * (D_ * E_) + (size_t)(dcol + c) * E_ + g * 8;
    }

    f32x4 acc[3] = {};

    for (int ks = 0; ks < E_ / 32; ks++) {
        int abyte = c * 2048 + (((ks * 32 + g * 8) * 2) ^ ((c & 7) << 4));
        u16x8 araw = *(const u16x8*)((char*)xl + abyte);
        bf16x8 av = __builtin_bit_cast(bf16x8, araw);
#pragma unroll
        for (int ct = 0; ct < 3; ct++) {
            bf16x8 bw = *(const bf16x8*)(wp[ct] + ks * 32);
            acc[ct] = __builtin_amdgcn_mfma_f32_16x16x32_bf16(av, bw, acc[ct], 0, 0, 0);
        }
    }

#pragma unroll
    for (int ct = 0; ct < 3; ct++) {
        int gc = wv * 48 + ct * 16;
        int proj = gc >> 7;
        int dcol = gc & 127;
        if (proj < 2) {
            u16* dst = proj ? k : q;
#pragma unroll
            for (int j = 0; j < 4; j++) {
                int row = mtile + g * 4 + j;
                dst[(size_t)row * D_ + dcol + c] = f2bf(acc[ct][j]);
            }
        } else {
            int srow = mtile + g * 4;
            int b = srow >> 12;
            int s = srow & 4095;
            ushort4 pk;
            pk.x = f2bf(acc[ct][0]);
            pk.y = f2bf(acc[ct][1]);
            pk.z = f2bf(acc[ct][2]);
            pk.w = f2bf(acc[ct][3]);
            *(ushort4*)(vT + ((size_t)(b * D_ + dcol + c)) * S_ + s) = pk;
        }
    }
}

// ---------------------------------------------------------------------------
// Kernel 2: flash attention, LDS-staged KV shared by 4 waves.
// Block: 256 thr (4 waves x 16 q-rows = 64 q-rows). Grid 256, XCD-chunk
// swizzled (chunk 32 -> 2 XCDs per batch, KV L2-resident).
// Per 64-kv tile: K (16KB) + V (16KB) staged to LDS via global_load_lds
// (zero VGPR), double-buffered; one __syncthreads per tile (its implicit
// vmcnt(0)+lgkmcnt(0) drain is the stage/compute sync).
// LDS tiles are XOR-swizzled byte^=(row&7)<<4: linear dest (gload_lds
// requirement) + inverse-swizzled global SOURCE + swizzled ds_read.
// r7 diagnosis: 32 global b128 loads/tile/wave with a 64-VGPR load window
// serialized on L2 latency; waves on a SIMD could not overlap. Staging
// converts those to conflict-free ds_read_b128.
// ---------------------------------------------------------------------------
__global__ __launch_bounds__(256) void attn_kernel(const u16* __restrict__ q,
                                                   const u16* __restrict__ k,
                                                   const u16* __restrict__ vT,
                                                   float* __restrict__ out) {
    // bijective XCD-chunk swizzle (nwg=256, 8 XCDs, chunk=32)
    int bid = blockIdx.x;
    int sw = (bid & 7) * 32 + (bid >> 3);
    const int b = sw >> 6;          // batch 0..3 (2 XCDs per batch)
    const int qt = sw & 63;         // q-tile 0..63 (64 rows)
    const int wv = threadIdx.x >> 6;
    const int l = threadIdx.x & 63;
    const int g = l >> 4;
    const int c = l & 15;
    const int qrow0 = qt * 64 + wv * 16;   // within batch

    __shared__ __align__(16) char kv_lds[2 * 32768];   // [buf][K 16KB | V 16KB]
    __shared__ __align__(16) u16 plds[4][1024];        // per-wave 2KB P buffer
    u16* pw = &plds[wv][0];

    const char* kbb = (const char*)(k + (size_t)b * S_ * D_);
    const char* vbb = (const char*)(vT + (size_t)b * D_ * S_);

    // Q fragments, hoisted (scaled already, via Wq)
    bf16x8 aq[4];
    const u16* qp = q + ((size_t)(b * S_ + qrow0 + c)) * D_ + g * 8;
#pragma unroll
    for (int ks = 0; ks < 4; ks++) aq[ks] = *(const bf16x8*)(qp + ks * 32);

    f32x4 o[8] = {};
    float m[4], ll[4];
#pragma unroll
    for (int j = 0; j < 4; j++) { m[j] = -1e30f; ll[j] = 0.0f; }

    // stage one 64-kv tile (K then V) into buffer `buf`; 8 instrs per wave
    auto STAGE = [&](int buf, int kvbase) {
#pragma unroll
        for (int ii = 0; ii < 4; ii++) {           // K: [64][256B] rows
            int i = wv * 4 + ii;                   // instr 0..15, 1KB each
            int row = (i * 1024 + l * 16) >> 8;    // = i*4 + (l>>4)
            int colb = (l & 15) * 16;
            const char* gp = kbb + (size_t)kvbase * 256 + (size_t)row * 256
                           + (colb ^ ((row & 7) << 4));
            gload16(gp, kv_lds + buf * 32768 + i * 1024);
        }
#pragma unroll
        for (int ii = 0; ii < 4; ii++) {           // V: [128][128B] rows
            int i = wv * 4 + ii;
            int row = i * 8 + (l >> 3);
            int colb = (l & 7) * 16;
            const char* gp = vbb + (size_t)row * 8192 + (size_t)kvbase * 2
                           + (colb ^ ((row & 7) << 4));
            gload16(gp, kv_lds + buf * 32768 + 16384 + i * 1024);
        }
    };

    STAGE(0, 0);
    __syncthreads();                 // drains vmcnt: buf0 ready
    int cur = 0;
    const int swz = (c & 7) << 4;

    for (int kt = 0; kt < S_ / 64; kt++) {
        if (kt < S_ / 64 - 1) STAGE(cur ^ 1, (kt + 1) * 64);

        const char* kbuf = kv_lds + cur * 32768;
        const char* vbuf = kbuf + 16384;

        // ---- S = Q K^T : 4 tiles of 16 kv-cols, K-dim 128 ----
        f32x4 s[4] = {};
#pragma unroll
        for (int t = 0; t < 4; t++) {
            int rb = (t * 16 + c) * 256;
#pragma unroll
            for (int ks = 0; ks < 4; ks++) {
                u16x8 kr = *(const u16x8*)(kbuf + rb + ((ks * 64 + g * 16) ^ swz));
                bf16x8 bk = __builtin_bit_cast(bf16x8, kr);
                s[t] = __builtin_amdgcn_mfma_f32_16x16x32_bf16(aq[ks], bk, s[t], 0, 0, 0);
            }
        }

        // ---- online softmax (rows live in 16-lane groups) ----
        float pv[4][4];
#pragma unroll
        for (int j = 0; j < 4; j++) {
            float tm = fmaxf(fmaxf(s[0][j], s[1][j]), fmaxf(s[2][j], s[3][j]));
            tm = fmaxf(tm, __shfl_xor(tm, 1));
            tm = fmaxf(tm, __shfl_xor(tm, 2));
            tm = fmaxf(tm, __shfl_xor(tm, 4));
            tm = fmaxf(tm, __shfl_xor(tm, 8));
            float mn = fmaxf(m[j], tm);
            float alpha = exp2f((m[j] - mn) * 1.44269504f);
            float rs = 0.f;
#pragma unroll
            for (int t = 0; t < 4; t++) {
                float p = exp2f((s[t][j] - mn) * 1.44269504f);
                pv[t][j] = p;
                rs += p;
            }
            rs += __shfl_xor(rs, 1);
            rs += __shfl_xor(rs, 2);
            rs += __shfl_xor(rs, 4);
            rs += __shfl_xor(rs, 8);
            ll[j] = ll[j] * alpha + rs;
            m[j] = mn;
#pragma unroll
            for (int ct = 0; ct < 8; ct++) o[ct][j] *= alpha;
        }

        // ---- P -> LDS (wave-private), XOR-swizzled ----
#pragma unroll
        for (int t = 0; t < 4; t++) {
#pragma unroll
            for (int j = 0; j < 4; j++) {
                int r = g * 4 + j;
                int cf = t * 16 + c;
                int slot = (cf >> 3) ^ ((r & 7) ^ ((r & 8) >> 2));
                pw[r * 64 + slot * 8 + (cf & 7)] = f2bf(pv[t][j]);
            }
        }

        // ---- PV: O += P[16,64] * V[64,128] ----
#pragma unroll
        for (int st = 0; st < 2; st++) {
            int rho = c;
            int sigma = g + st * 4;
            int slot = sigma ^ ((rho & 7) ^ ((rho & 8) >> 2));
            u16x8 praw = *(const u16x8*)(pw + rho * 64 + slot * 8);
            bf16x8 pa = __builtin_bit_cast(bf16x8, praw);
#pragma unroll
            for (int ct = 0; ct < 8; ct++) {
                int rb = (ct * 16 + c) * 128;
                u16x8 vr = *(const u16x8*)(vbuf + rb + ((st * 64 + g * 16) ^ swz));
                bf16x8 bv = __builtin_bit_cast(bf16x8, vr);
                o[ct] = __builtin_amdgcn_mfma_f32_16x16x32_bf16(pa, bv, o[ct], 0, 0, 0);
            }
        }

        __syncthreads();    // drain staging vmcnt + tile barrier
        cur ^= 1;
    }

    // ---- epilogue: divide by l, store FLOAT32 directly ----
    float rinv[4];
#pragma unroll
    for (int j = 0; j < 4; j++) rinv[j] = 1.0f / ll[j];
#pragma unroll
    for (int ct = 0; ct < 8; ct++) {
#pragma unroll
        for (int j = 0; j < 4; j++) {
            int row = b * S_ + qrow0 + g * 4 + j;
            out[(size_t)row * D_ + ct * 16 + c] = o[ct][j] * rinv[j];
        }
    }
}

extern "C" void kernel_launch(void* const* d_in, const int* in_sizes, int n_in,
                              void* d_out, int out_size, void* d_ws, size_t ws_size,
                              hipStream_t stream) {
    const float* x  = (const float*)d_in[0];
    const float* Wq = (const float*)d_in[1];
    const float* Wk = (const float*)d_in[2];
    const float* Wv = (const float*)d_in[3];
    float* out = (float*)d_out;   // reference output dtype is float32

    // workspace layout (bytes): q 4MB | k 4MB | vT 4MB | Wt 768KB
    u16* q  = (u16*)d_ws;
    u16* k  = q  + (size_t)B_ * S_ * D_;
    u16* vT = k  + (size_t)B_ * S_ * D_;
    u16* Wt = vT + (size_t)B_ * S_ * D_;

    wt_kernel<<<(3 * D_ * E_) / 256, 256, 0, stream>>>(Wq, Wk, Wv, Wt);
    qkv_fused<<<(B_ * S_) / 16, 512, 0, stream>>>(x, Wt, q, k, vT);
    attn_kernel<<<(B_ * S_) / 64, 256, 0, stream>>>(q, k, vT, out);
}

// Round 9
// 194.352 us; speedup vs baseline: 2.6499x; 1.2249x over previous
//
#include <hip/hip_runtime.h>
#include <hip/hip_bf16.h>

#define B_ 4
#define S_ 4096
#define E_ 1024
#define D_ 128

typedef unsigned short u16;
typedef __bf16 bf16x8 __attribute__((ext_vector_type(8)));
typedef unsigned short u16x8 __attribute__((ext_vector_type(8)));
typedef float f32x4 __attribute__((ext_vector_type(4)));

__device__ inline u16 f2bf(float f) {
    __bf16 h = (__bf16)f;
    return __builtin_bit_cast(u16, h);
}

// direct global->LDS DMA, 16B per lane, no VGPR round-trip
__device__ inline void gload16(const void* g, void* l) {
    __builtin_amdgcn_global_load_lds(
        (const __attribute__((address_space(1))) void*)g,
        (__attribute__((address_space(3))) void*)l, 16, 0, 0);
}

// ---------------------------------------------------------------------------
// Kernel 0: W [E,D] f32 -> Wt [3][D][E] bf16 (proj 0 pre-scaled by 1/sqrt(D))
// ---------------------------------------------------------------------------
__global__ __launch_bounds__(256) void wt_kernel(const float* __restrict__ Wq,
                                                 const float* __restrict__ Wk,
                                                 const float* __restrict__ Wv,
                                                 u16* __restrict__ Wt) {
    int tid = blockIdx.x * 256 + threadIdx.x;       // 0 .. 3*131072-1
    int w = tid >> 17;                               // 131072 = 2^17
    int rem = tid & 131071;
    int d = rem >> 10;
    int e = rem & 1023;
    const float* W = (w == 0) ? Wq : ((w == 1) ? Wk : Wv);
    float v = W[e * D_ + d];
    if (w == 0) v *= 0.08838834764831845f;           // 1/sqrt(128)
    Wt[tid] = f2bf(v);
}

// ---------------------------------------------------------------------------
// Kernel 1: FUSED QKV projection, 512 threads (8 waves) per block.
// Block: 16 rows x 384 cols; wave wv covers cols [wv*48, wv*48+48) = 3
// MFMA col-tiles. x staged ONCE per block in LDS (bf16, XOR-swizzled).
// ---------------------------------------------------------------------------
__global__ __launch_bounds__(512) void qkv_fused(const float* __restrict__ x,
                                                 const u16* __restrict__ Wt,
                                                 u16* __restrict__ q,
                                                 u16* __restrict__ k,
                                                 u16* __restrict__ vT) {
    const int mtile = blockIdx.x * 16;
    const int wv = threadIdx.x >> 6;       // 0..7
    const int l = threadIdx.x & 63;
    const int g = l >> 4;
    const int c = l & 15;

    __shared__ __align__(16) u16 xl[16 * 1024];   // 32 KB, XOR-swizzled rows

    // cooperative stage: 512 threads, 8 iterations, 2 rows per iteration
#pragma unroll 4
    for (int i = 0; i < 8; i++) {
        int row = i * 2 + (threadIdx.x >> 8);
        int col = (threadIdx.x & 255) * 4;
        float4 xv = *(const float4*)(x + (size_t)(mtile + row) * E_ + col);
        ushort4 pk;
        pk.x = f2bf(xv.x); pk.y = f2bf(xv.y);
        pk.z = f2bf(xv.z); pk.w = f2bf(xv.w);
        int byte = row * 2048 + ((col * 2) ^ ((row & 7) << 4));
        *(ushort4*)((char*)xl + byte) = pk;
    }
    __syncthreads();

    const u16* wp[3];
#pragma unroll
    for (int ct = 0; ct < 3; ct++) {
        int gc = wv * 48 + ct * 16;          // global output col (tile base)
        int proj = gc >> 7;
        int dcol = gc & 127;
        wp[ct] = Wt + (size_t)proj * (D_ * E_) + (size_t)(dcol + c) * E_ + g * 8;
    }

    f32x4 acc[3] = {};

    for (int ks = 0; ks < E_ / 32; ks++) {
        int abyte = c * 2048 + (((ks * 32 + g * 8) * 2) ^ ((c & 7) << 4));
        u16x8 araw = *(const u16x8*)((char*)xl + abyte);
        bf16x8 av = __builtin_bit_cast(bf16x8, araw);
#pragma unroll
        for (int ct = 0; ct < 3; ct++) {
            bf16x8 bw = *(const bf16x8*)(wp[ct] + ks * 32);
            acc[ct] = __builtin_amdgcn_mfma_f32_16x16x32_bf16(av, bw, acc[ct], 0, 0, 0);
        }
    }

#pragma unroll
    for (int ct = 0; ct < 3; ct++) {
        int gc = wv * 48 + ct * 16;
        int proj = gc >> 7;
        int dcol = gc & 127;
        if (proj < 2) {
            u16* dst = proj ? k : q;
#pragma unroll
            for (int j = 0; j < 4; j++) {
                int row = mtile + g * 4 + j;
                dst[(size_t)row * D_ + dcol + c] = f2bf(acc[ct][j]);
            }
        } else {
            int srow = mtile + g * 4;
            int b = srow >> 12;
            int s = srow & 4095;
            ushort4 pk;
            pk.x = f2bf(acc[ct][0]);
            pk.y = f2bf(acc[ct][1]);
            pk.z = f2bf(acc[ct][2]);
            pk.w = f2bf(acc[ct][3]);
            *(ushort4*)(vT + ((size_t)(b * D_ + dcol + c)) * S_ + s) = pk;
        }
    }
}

// ---------------------------------------------------------------------------
// Kernel 2: flash attention, even/odd KV-tile split across two 4-wave groups.
// 512 thr = 8 waves. Waves 0-3 (grp 0): even KV tiles; waves 4-7 (grp 1):
// odd KV tiles; both groups own the SAME 64 q-rows (wave wq = wv&3 handles
// rows wq*16..wq*16+16). Per round: compute tile pair (2t, 2t+1) from LDS
// bufs while staging pair (2t+2, 2t+3) into the other two bufs
// (global_load_lds, zero VGPR); one __syncthreads per round (its implicit
// vmcnt drain is the stage sync). 4 x 32KB KV bufs + 16KB plds = ~144KB
// -> 1 block/CU x 8 waves = 2 waves/SIMD (r8 had 1 wave/SIMD, 60% stall).
// Epilogue: 2-way (m,l,o) merge through LDS (grp 1 -> LDS, grp 0 merges).
// ---------------------------------------------------------------------------
__global__ __launch_bounds__(512) void attn_kernel(const u16* __restrict__ q,
                                                   const u16* __restrict__ k,
                                                   const u16* __restrict__ vT,
                                                   float* __restrict__ out) {
    // bijective XCD-chunk swizzle (nwg=256, 8 XCDs, chunk=32)
    int bid = blockIdx.x;
    int sw = (bid & 7) * 32 + (bid >> 3);
    const int b = sw >> 6;          // batch 0..3 (2 XCDs per batch)
    const int qt = sw & 63;         // q-tile 0..63 (64 rows)
    const int wv = threadIdx.x >> 6;    // 0..7
    const int grp = wv >> 2;            // 0 = even tiles, 1 = odd tiles
    const int wq = wv & 3;              // q-subtile within block
    const int l = threadIdx.x & 63;
    const int g = l >> 4;
    const int c = l & 15;
    const int qrow0 = qt * 64 + wq * 16;   // within batch

    __shared__ __align__(16) char kv_lds[4 * 32768];   // 4 KV bufs (K 16K | V 16K)
    __shared__ __align__(16) u16 plds[8][1024];        // per-wave 2KB P buffer
    __shared__ float cmB[64], clB[64];
    u16* pw = &plds[wv][0];

    const char* kbb = (const char*)(k + (size_t)b * S_ * D_);
    const char* vbb = (const char*)(vT + (size_t)b * D_ * S_);

    // Q fragments, hoisted (scaled already, via Wq)
    bf16x8 aq[4];
    const u16* qp = q + ((size_t)(b * S_ + qrow0 + c)) * D_ + g * 8;
#pragma unroll
    for (int ks = 0; ks < 4; ks++) aq[ks] = *(const bf16x8*)(qp + ks * 32);

    f32x4 o[8] = {};
    float m[4], ll[4];
#pragma unroll
    for (int j = 0; j < 4; j++) { m[j] = -1e30f; ll[j] = 0.0f; }

    // stage one 64-kv tile (K then V) into buffer `buf`; this group's 4 waves
    // (indexed sub=wv&3) move 32KB; global source is inverse-XOR-swizzled.
    auto STAGE = [&](int buf, int kvbase) {
        int sub = wq;
#pragma unroll
        for (int ii = 0; ii < 4; ii++) {           // K: [64][256B] rows
            int i = sub * 4 + ii;                  // instr 0..15, 1KB each
            int row = i * 4 + (l >> 4);
            int colb = (l & 15) * 16;
            const char* gp = kbb + (size_t)kvbase * 256 + (size_t)row * 256
                           + (colb ^ ((row & 7) << 4));
            gload16(gp, kv_lds + buf * 32768 + i * 1024);
        }
#pragma unroll
        for (int ii = 0; ii < 4; ii++) {           // V: [128][128B] rows
            int i = sub * 4 + ii;
            int row = i * 8 + (l >> 3);
            int colb = (l & 7) * 16;
            const char* gp = vbb + (size_t)row * 8192 + (size_t)kvbase * 2
                           + (colb ^ ((row & 7) << 4));
            gload16(gp, kv_lds + buf * 32768 + 16384 + i * 1024);
        }
    };

    // prologue: group g stages tile g into buf g
    STAGE(grp, grp * 64);
    __syncthreads();                 // drains vmcnt: bufs 0,1 ready
    const int swz = (c & 7) << 4;

    for (int t = 0; t < 32; t++) {
        const int mytile = 2 * t + grp;
        if (t < 31) STAGE((mytile + 2) & 3, (mytile + 2) * 64);

        const char* kbuf = kv_lds + (mytile & 3) * 32768;
        const char* vbuf = kbuf + 16384;
        const int kvbase = 0;  (void)kvbase;

        // ---- S = Q K^T : 4 tiles of 16 kv-cols, K-dim 128 ----
        f32x4 s[4] = {};
#pragma unroll
        for (int tt = 0; tt < 4; tt++) {
            int rb = (tt * 16 + c) * 256;
#pragma unroll
            for (int ks = 0; ks < 4; ks++) {
                u16x8 kr = *(const u16x8*)(kbuf + rb + ((ks * 64 + g * 16) ^ swz));
                bf16x8 bk = __builtin_bit_cast(bf16x8, kr);
                s[tt] = __builtin_amdgcn_mfma_f32_16x16x32_bf16(aq[ks], bk, s[tt], 0, 0, 0);
            }
        }

        // ---- online softmax (rows live in 16-lane groups) ----
        float pv[4][4];
#pragma unroll
        for (int j = 0; j < 4; j++) {
            float tm = fmaxf(fmaxf(s[0][j], s[1][j]), fmaxf(s[2][j], s[3][j]));
            tm = fmaxf(tm, __shfl_xor(tm, 1));
            tm = fmaxf(tm, __shfl_xor(tm, 2));
            tm = fmaxf(tm, __shfl_xor(tm, 4));
            tm = fmaxf(tm, __shfl_xor(tm, 8));
            float mn = fmaxf(m[j], tm);
            float alpha = exp2f((m[j] - mn) * 1.44269504f);
            float rs = 0.f;
#pragma unroll
            for (int tt = 0; tt < 4; tt++) {
                float p = exp2f((s[tt][j] - mn) * 1.44269504f);
                pv[tt][j] = p;
                rs += p;
            }
            rs += __shfl_xor(rs, 1);
            rs += __shfl_xor(rs, 2);
            rs += __shfl_xor(rs, 4);
            rs += __shfl_xor(rs, 8);
            ll[j] = ll[j] * alpha + rs;
            m[j] = mn;
#pragma unroll
            for (int ct = 0; ct < 8; ct++) o[ct][j] *= alpha;
        }

        // ---- P -> LDS (wave-private), XOR-swizzled ----
#pragma unroll
        for (int tt = 0; tt < 4; tt++) {
#pragma unroll
            for (int j = 0; j < 4; j++) {
                int r = g * 4 + j;
                int cf = tt * 16 + c;
                int slot = (cf >> 3) ^ ((r & 7) ^ ((r & 8) >> 2));
                pw[r * 64 + slot * 8 + (cf & 7)] = f2bf(pv[tt][j]);
            }
        }

        // ---- PV: O += P[16,64] * V[64,128] ----
#pragma unroll
        for (int st = 0; st < 2; st++) {
            int rho = c;
            int sigma = g + st * 4;
            int slot = sigma ^ ((rho & 7) ^ ((rho & 8) >> 2));
            u16x8 praw = *(const u16x8*)(pw + rho * 64 + slot * 8);
            bf16x8 pa = __builtin_bit_cast(bf16x8, praw);
#pragma unroll
            for (int ct = 0; ct < 8; ct++) {
                int rb = (ct * 16 + c) * 128;
                u16x8 vr = *(const u16x8*)(vbuf + rb + ((st * 64 + g * 16) ^ swz));
                bf16x8 bv = __builtin_bit_cast(bf16x8, vr);
                o[ct] = __builtin_amdgcn_mfma_f32_16x16x32_bf16(pa, bv, o[ct], 0, 0, 0);
            }
        }

        __syncthreads();    // drain staging vmcnt + round barrier
    }

    // ---- 2-way merge: grp 1 -> LDS, grp 0 merges and stores ----
    float* co = (float*)kv_lds;     // 32KB, staging complete
    if (grp == 1) {
#pragma unroll
        for (int ct = 0; ct < 8; ct++) {
#pragma unroll
            for (int j = 0; j < 4; j++)
                co[(size_t)(wq * 16 + g * 4 + j) * 128 + ct * 16 + c] = o[ct][j];
        }
        if (c == 0) {
#pragma unroll
            for (int j = 0; j < 4; j++) {
                cmB[wq * 16 + g * 4 + j] = m[j];
                clB[wq * 16 + g * 4 + j] = ll[j];
            }
        }
    }
    __syncthreads();
    if (grp == 0) {
#pragma unroll
        for (int j = 0; j < 4; j++) {
            int r = wq * 16 + g * 4 + j;
            float mB = cmB[r], lB = clB[r];
            float M = fmaxf(m[j], mB);
            float eA = exp2f((m[j] - M) * 1.44269504f);
            float eB = exp2f((mB - M) * 1.44269504f);
            float rL = 1.0f / (ll[j] * eA + lB * eB);
            float* op = out + ((size_t)(b * S_ + qt * 64 + r)) * D_;
#pragma unroll
            for (int ct = 0; ct < 8; ct++) {
                op[ct * 16 + c] = (o[ct][j] * eA + co[(size_t)r * 128 + ct * 16 + c] * eB) * rL;
            }
        }
    }
}

extern "C" void kernel_launch(void* const* d_in, const int* in_sizes, int n_in,
                              void* d_out, int out_size, void* d_ws, size_t ws_size,
                              hipStream_t stream) {
    const float* x  = (const float*)d_in[0];
    const float* Wq = (const float*)d_in[1];
    const float* Wk = (const float*)d_in[2];
    const float* Wv = (const float*)d_in[3];
    float* out = (float*)d_out;   // reference output dtype is float32

    // workspace layout (bytes): q 4MB | k 4MB | vT 4MB | Wt 768KB
    u16* q  = (u16*)d_ws;
    u16* k  = q  + (size_t)B_ * S_ * D_;
    u16* vT = k  + (size_t)B_ * S_ * D_;
    u16* Wt = vT + (size_t)B_ * S_ * D_;

    wt_kernel<<<(3 * D_ * E_) / 256, 256, 0, stream>>>(Wq, Wk, Wv, Wt);
    qkv_fused<<<(B_ * S_) / 16, 512, 0, stream>>>(x, Wt, q, k, vT);
    attn_kernel<<<(B_ * S_) / 64, 512, 0, stream>>>(q, k, vT, out);
}

// Round 10
// 170.033 us; speedup vs baseline: 3.0289x; 1.1430x over previous
//
#include <hip/hip_runtime.h>
#include <hip/hip_bf16.h>

#define B_ 4
#define S_ 4096
#define E_ 1024
#define D_ 128

typedef unsigned short u16;
typedef __bf16 bf16x8 __attribute__((ext_vector_type(8)));
typedef unsigned short u16x8 __attribute__((ext_vector_type(8)));
typedef float f32x4 __attribute__((ext_vector_type(4)));

__device__ inline u16 f2bf(float f) {
    __bf16 h = (__bf16)f;
    return __builtin_bit_cast(u16, h);
}

// direct global->LDS DMA, 16B per lane, no VGPR round-trip
__device__ inline void gload16(const void* g, void* l) {
    __builtin_amdgcn_global_load_lds(
        (const __attribute__((address_space(1))) void*)g,
        (__attribute__((address_space(3))) void*)l, 16, 0, 0);
}

// ---------------------------------------------------------------------------
// Kernel 0: W [E,D] f32 -> Wt [3][D][E] bf16 (proj 0 pre-scaled by 1/sqrt(D))
// ---------------------------------------------------------------------------
__global__ __launch_bounds__(256) void wt_kernel(const float* __restrict__ Wq,
                                                 const float* __restrict__ Wk,
                                                 const float* __restrict__ Wv,
                                                 u16* __restrict__ Wt) {
    int tid = blockIdx.x * 256 + threadIdx.x;       // 0 .. 3*131072-1
    int w = tid >> 17;                               // 131072 = 2^17
    int rem = tid & 131071;
    int d = rem >> 10;
    int e = rem & 1023;
    const float* W = (w == 0) ? Wq : ((w == 1) ? Wk : Wv);
    float v = W[e * D_ + d];
    if (w == 0) v *= 0.08838834764831845f;           // 1/sqrt(128)
    Wt[tid] = f2bf(v);
}

// ---------------------------------------------------------------------------
// Kernel 1: QKV as a proper LDS-staged GEMM. C[16384,384] = x * [Wq|Wk|Wv].
// Grid 256 (M-tile 64), 512 thr = 8 waves tiled 2x4: wave (wr,wc) owns
// rows wr*32+{0,16}, cols wc*96 (6 col-tiles). K-loop BK=32, 32 steps,
// double-buffered W-tile in LDS.
// W-tile stored in FRAGMENT ORDER [ct][lane][16B]: B-frag ds_read_b128 at
// base+l*16 is linear in lane (zero bank conflicts); the per-lane GLOBAL
// source address of global_load_lds realizes the layout (linear LDS dest).
// A-frags: f32 direct from global (L2-warm, 128B/row per 16-lane group).
// r9 diagnosis: old qkv was latency-bound (VGPR 32, 3-deep W loads from
// global per wave, M-tile 16) -> MfmaUtil 4.6%.
// ---------------------------------------------------------------------------
__global__ __launch_bounds__(512, 4) void qkv_fused(const float* __restrict__ x,
                                                    const u16* __restrict__ Wt,
                                                    u16* __restrict__ q,
                                                    u16* __restrict__ k,
                                                    u16* __restrict__ vT) {
    const int mrow0 = blockIdx.x * 64;
    const int wv = threadIdx.x >> 6;   // 0..7
    const int l = threadIdx.x & 63;
    const int g = l >> 4;
    const int c = l & 15;
    const int wr = wv >> 2;            // 0..1 (32-row half)
    const int wc = wv & 3;             // 0..3 (96-col group)

    __shared__ __align__(16) char wlds[2][24 * 1024];   // 48 KB dbuf W-tile

    // stage W k-slice [kbase, kbase+32) into buf: 3 instrs per wave.
    // logical: wtile[ct][lane][8 u16] ; lane l -> col dcol+c, k kbase+g*8..+8
    auto STAGE_W = [&](int buf, int kbase) {
#pragma unroll
        for (int ii = 0; ii < 3; ii++) {
            int ct = wv * 3 + ii;                  // 0..23
            int proj = ct >> 3;
            int dcol = (ct & 7) * 16;
            const u16* gp = Wt + ((size_t)(proj * 128 + dcol + c) * 1024 + kbase + g * 8);
            gload16(gp, wlds[buf] + ct * 1024);
        }
    };

    STAGE_W(0, 0);

    const float* xrow[2];
#pragma unroll
    for (int sub = 0; sub < 2; sub++)
        xrow[sub] = x + (size_t)(mrow0 + wr * 32 + sub * 16 + c) * E_ + g * 8;

    f32x4 acc[2][6] = {};
    __syncthreads();                 // buf0 staged (implicit vmcnt drain)

    int buf = 0;
    for (int ks = 0; ks < 32; ks++) {
        if (ks < 31) STAGE_W(buf ^ 1, (ks + 1) * 32);

        // A-frags: 2 x 32B f32 -> bf16x8
        bf16x8 av[2];
#pragma unroll
        for (int sub = 0; sub < 2; sub++) {
            const float4 x0 = *(const float4*)(xrow[sub] + ks * 32);
            const float4 x1 = *(const float4*)(xrow[sub] + ks * 32 + 4);
            union { bf16x8 v; __bf16 e[8]; } a;
            a.e[0] = (__bf16)x0.x; a.e[1] = (__bf16)x0.y;
            a.e[2] = (__bf16)x0.z; a.e[3] = (__bf16)x0.w;
            a.e[4] = (__bf16)x1.x; a.e[5] = (__bf16)x1.y;
            a.e[6] = (__bf16)x1.z; a.e[7] = (__bf16)x1.w;
            av[sub] = a.v;
        }

#pragma unroll
        for (int ct = 0; ct < 6; ct++) {
            u16x8 braw = *(const u16x8*)(wlds[buf] + (wc * 6 + ct) * 1024 + l * 16);
            bf16x8 bw = __builtin_bit_cast(bf16x8, braw);
#pragma unroll
            for (int sub = 0; sub < 2; sub++)
                acc[sub][ct] = __builtin_amdgcn_mfma_f32_16x16x32_bf16(av[sub], bw, acc[sub][ct], 0, 0, 0);
        }

        __syncthreads();             // reads done + next-buf staging drained
        buf ^= 1;
    }

    // ---- epilogue ----
#pragma unroll
    for (int sub = 0; sub < 2; sub++) {
#pragma unroll
        for (int ct = 0; ct < 6; ct++) {
            int gc = (wc * 6 + ct) * 16;
            int proj = gc >> 7;
            int dcol = gc & 127;
            if (proj < 2) {
                u16* dst = proj ? k : q;
#pragma unroll
                for (int j = 0; j < 4; j++) {
                    int row = mrow0 + wr * 32 + sub * 16 + g * 4 + j;
                    dst[(size_t)row * D_ + dcol + c] = f2bf(acc[sub][ct][j]);
                }
            } else {
                int srow = mrow0 + wr * 32 + sub * 16 + g * 4;
                int b = srow >> 12;
                int s = srow & 4095;
                ushort4 pk;
                pk.x = f2bf(acc[sub][ct][0]);
                pk.y = f2bf(acc[sub][ct][1]);
                pk.z = f2bf(acc[sub][ct][2]);
                pk.w = f2bf(acc[sub][ct][3]);
                *(ushort4*)(vT + ((size_t)(b * D_ + dcol + c)) * S_ + s) = pk;
            }
        }
    }
}

// ---------------------------------------------------------------------------
// Kernel 2: flash attention, even/odd KV-tile split across two 4-wave groups.
// (unchanged from r9: 512 thr, LDS-staged dbuf KV, 2 waves/SIMD, ~84us)
// ---------------------------------------------------------------------------
__global__ __launch_bounds__(512) void attn_kernel(const u16* __restrict__ q,
                                                   const u16* __restrict__ k,
                                                   const u16* __restrict__ vT,
                                                   float* __restrict__ out) {
    // bijective XCD-chunk swizzle (nwg=256, 8 XCDs, chunk=32)
    int bid = blockIdx.x;
    int sw = (bid & 7) * 32 + (bid >> 3);
    const int b = sw >> 6;          // batch 0..3 (2 XCDs per batch)
    const int qt = sw & 63;         // q-tile 0..63 (64 rows)
    const int wv = threadIdx.x >> 6;    // 0..7
    const int grp = wv >> 2;            // 0 = even tiles, 1 = odd tiles
    const int wq = wv & 3;              // q-subtile within block
    const int l = threadIdx.x & 63;
    const int g = l >> 4;
    const int c = l & 15;
    const int qrow0 = qt * 64 + wq * 16;   // within batch

    __shared__ __align__(16) char kv_lds[4 * 32768];   // 4 KV bufs (K 16K | V 16K)
    __shared__ __align__(16) u16 plds[8][1024];        // per-wave 2KB P buffer
    __shared__ float cmB[64], clB[64];
    u16* pw = &plds[wv][0];

    const char* kbb = (const char*)(k + (size_t)b * S_ * D_);
    const char* vbb = (const char*)(vT + (size_t)b * D_ * S_);

    // Q fragments, hoisted (scaled already, via Wq)
    bf16x8 aq[4];
    const u16* qp = q + ((size_t)(b * S_ + qrow0 + c)) * D_ + g * 8;
#pragma unroll
    for (int ks = 0; ks < 4; ks++) aq[ks] = *(const bf16x8*)(qp + ks * 32);

    f32x4 o[8] = {};
    float m[4], ll[4];
#pragma unroll
    for (int j = 0; j < 4; j++) { m[j] = -1e30f; ll[j] = 0.0f; }

    auto STAGE = [&](int buf, int kvbase) {
        int sub = wq;
#pragma unroll
        for (int ii = 0; ii < 4; ii++) {           // K: [64][256B] rows
            int i = sub * 4 + ii;                  // instr 0..15, 1KB each
            int row = i * 4 + (l >> 4);
            int colb = (l & 15) * 16;
            const char* gp = kbb + (size_t)kvbase * 256 + (size_t)row * 256
                           + (colb ^ ((row & 7) << 4));
            gload16(gp, kv_lds + buf * 32768 + i * 1024);
        }
#pragma unroll
        for (int ii = 0; ii < 4; ii++) {           // V: [128][128B] rows
            int i = sub * 4 + ii;
            int row = i * 8 + (l >> 3);
            int colb = (l & 7) * 16;
            const char* gp = vbb + (size_t)row * 8192 + (size_t)kvbase * 2
                           + (colb ^ ((row & 7) << 4));
            gload16(gp, kv_lds + buf * 32768 + 16384 + i * 1024);
        }
    };

    STAGE(grp, grp * 64);
    __syncthreads();                 // drains vmcnt: bufs 0,1 ready
    const int swz = (c & 7) << 4;

    for (int t = 0; t < 32; t++) {
        const int mytile = 2 * t + grp;
        if (t < 31) STAGE((mytile + 2) & 3, (mytile + 2) * 64);

        const char* kbuf = kv_lds + (mytile & 3) * 32768;
        const char* vbuf = kbuf + 16384;

        // ---- S = Q K^T : 4 tiles of 16 kv-cols, K-dim 128 ----
        f32x4 s[4] = {};
#pragma unroll
        for (int tt = 0; tt < 4; tt++) {
            int rb = (tt * 16 + c) * 256;
#pragma unroll
            for (int ks = 0; ks < 4; ks++) {
                u16x8 kr = *(const u16x8*)(kbuf + rb + ((ks * 64 + g * 16) ^ swz));
                bf16x8 bk = __builtin_bit_cast(bf16x8, kr);
                s[tt] = __builtin_amdgcn_mfma_f32_16x16x32_bf16(aq[ks], bk, s[tt], 0, 0, 0);
            }
        }

        // ---- online softmax (rows live in 16-lane groups) ----
        float pv[4][4];
#pragma unroll
        for (int j = 0; j < 4; j++) {
            float tm = fmaxf(fmaxf(s[0][j], s[1][j]), fmaxf(s[2][j], s[3][j]));
            tm = fmaxf(tm, __shfl_xor(tm, 1));
            tm = fmaxf(tm, __shfl_xor(tm, 2));
            tm = fmaxf(tm, __shfl_xor(tm, 4));
            tm = fmaxf(tm, __shfl_xor(tm, 8));
            float mn = fmaxf(m[j], tm);
            float alpha = exp2f((m[j] - mn) * 1.44269504f);
            float rs = 0.f;
#pragma unroll
            for (int tt = 0; tt < 4; tt++) {
                float p = exp2f((s[tt][j] - mn) * 1.44269504f);
                pv[tt][j] = p;
                rs += p;
            }
            rs += __shfl_xor(rs, 1);
            rs += __shfl_xor(rs, 2);
            rs += __shfl_xor(rs, 4);
            rs += __shfl_xor(rs, 8);
            ll[j] = ll[j] * alpha + rs;
            m[j] = mn;
#pragma unroll
            for (int ct = 0; ct < 8; ct++) o[ct][j] *= alpha;
        }

        // ---- P -> LDS (wave-private), XOR-swizzled ----
#pragma unroll
        for (int tt = 0; tt < 4; tt++) {
#pragma unroll
            for (int j = 0; j < 4; j++) {
                int r = g * 4 + j;
                int cf = tt * 16 + c;
                int slot = (cf >> 3) ^ ((r & 7) ^ ((r & 8) >> 2));
                pw[r * 64 + slot * 8 + (cf & 7)] = f2bf(pv[tt][j]);
            }
        }

        // ---- PV: O += P[16,64] * V[64,128] ----
#pragma unroll
        for (int st = 0; st < 2; st++) {
            int rho = c;
            int sigma = g + st * 4;
            int slot = sigma ^ ((rho & 7) ^ ((rho & 8) >> 2));
            u16x8 praw = *(const u16x8*)(pw + rho * 64 + slot * 8);
            bf16x8 pa = __builtin_bit_cast(bf16x8, praw);
#pragma unroll
            for (int ct = 0; ct < 8; ct++) {
                int rb = (ct * 16 + c) * 128;
                u16x8 vr = *(const u16x8*)(vbuf + rb + ((st * 64 + g * 16) ^ swz));
                bf16x8 bv = __builtin_bit_cast(bf16x8, vr);
                o[ct] = __builtin_amdgcn_mfma_f32_16x16x32_bf16(pa, bv, o[ct], 0, 0, 0);
            }
        }

        __syncthreads();    // drain staging vmcnt + round barrier
    }

    // ---- 2-way merge: grp 1 -> LDS, grp 0 merges and stores ----
    float* co = (float*)kv_lds;     // 32KB, staging complete
    if (grp == 1) {
#pragma unroll
        for (int ct = 0; ct < 8; ct++) {
#pragma unroll
            for (int j = 0; j < 4; j++)
                co[(size_t)(wq * 16 + g * 4 + j) * 128 + ct * 16 + c] = o[ct][j];
        }
        if (c == 0) {
#pragma unroll
            for (int j = 0; j < 4; j++) {
                cmB[wq * 16 + g * 4 + j] = m[j];
                clB[wq * 16 + g * 4 + j] = ll[j];
            }
        }
    }
    __syncthreads();
    if (grp == 0) {
#pragma unroll
        for (int j = 0; j < 4; j++) {
            int r = wq * 16 + g * 4 + j;
            float mB = cmB[r], lB = clB[r];
            float M = fmaxf(m[j], mB);
            float eA = exp2f((m[j] - M) * 1.44269504f);
            float eB = exp2f((mB - M) * 1.44269504f);
            float rL = 1.0f / (ll[j] * eA + lB * eB);
            float* op = out + ((size_t)(b * S_ + qt * 64 + r)) * D_;
#pragma unroll
            for (int ct = 0; ct < 8; ct++) {
                op[ct * 16 + c] = (o[ct][j] * eA + co[(size_t)r * 128 + ct * 16 + c] * eB) * rL;
            }
        }
    }
}

extern "C" void kernel_launch(void* const* d_in, const int* in_sizes, int n_in,
                              void* d_out, int out_size, void* d_ws, size_t ws_size,
                              hipStream_t stream) {
    const float* x  = (const float*)d_in[0];
    const float* Wq = (const float*)d_in[1];
    const float* Wk = (const float*)d_in[2];
    const float* Wv = (const float*)d_in[3];
    float* out = (float*)d_out;   // reference output dtype is float32

    // workspace layout (bytes): q 4MB | k 4MB | vT 4MB | Wt 768KB
    u16* q  = (u16*)d_ws;
    u16* k  = q  + (size_t)B_ * S_ * D_;
    u16* vT = k  + (size_t)B_ * S_ * D_;
    u16* Wt = vT + (size_t)B_ * S_ * D_;

    wt_kernel<<<(3 * D_ * E_) / 256, 256, 0, stream>>>(Wq, Wk, Wv, Wt);
    qkv_fused<<<(B_ * S_) / 64, 512, 0, stream>>>(x, Wt, q, k, vT);
    attn_kernel<<<(B_ * S_) / 64, 512, 0, stream>>>(q, k, vT, out);
}